// Round 17
// baseline (104.462 us; speedup 1.0000x reference)
//
#include <hip/hip_runtime.h>

#define EPS 1e-7f

constexpr int NPRED = 8192;
constexpr int NTGT  = 4096;
constexpr int BLOCK = 512;           // 8 waves; ONE PRED PER THREAD
constexpr int TS    = 16;            // target slices
constexpr int TSL   = NTGT / TS;     // 256 targets per slice
constexpr int PBLK  = NPRED / BLOCK; // 16 pred-groups
constexpr int GRID  = PBLK * TS;     // 256 blocks -> 1/CU, 8 waves/CU

__device__ __forceinline__ unsigned sortable_key(float f) {
  unsigned b = __float_as_uint(f);
  return (b & 0x80000000u) ? ~b : (b | 0x80000000u);
}

// Each thread owns one pred; targets are wave-uniform (scalar/broadcast loads).
// No LDS, no shuffles, no atomics: per-slice argmax written as packed u64.
__global__ __launch_bounds__(BLOCK)
void diou_argmax(const float4* __restrict__ pred,
                 const float4* __restrict__ tgt,
                 unsigned long long* __restrict__ pk) {
  const int pg  = blockIdx.x % PBLK;
  const int tq  = blockIdx.x / PBLK;
  const int pid = pg * BLOCK + threadIdx.x;

  const float4 p     = pred[pid];
  const float  paeps = (p.z - p.x) * (p.w - p.y) + EPS;  // xyxy-interp area + eps
  const float4* ts   = tgt + tq * TSL;

  float bestV = -INFINITY;
  int   bestJ = 0;

#pragma unroll 8
  for (int j = 0; j < TSL; ++j) {
    float4 t  = ts[j];                 // uniform address -> SGPR/broadcast load
    float  ta = (t.z - t.x) * (t.w - t.y);
    float w = fminf(p.z, t.z) - fmaxf(p.x, t.x);
    float h = fminf(p.w, t.w) - fmaxf(p.y, t.y);
    w = fmaxf(w, 0.f);
    h = fmaxf(h, 0.f);
    float inter = w * h;
    float den   = (paeps + ta) - inter;
    float iou   = inter * __builtin_amdgcn_rcpf(den);
    // strict > keeps the FIRST max (j ascends); candidate j is wave-uniform
    bool gt = iou > bestV;
    bestV = gt ? iou : bestV;
    bestJ = gt ? j : bestJ;
  }

  bestV += 0.0f;                       // normalize -0 -> +0 for key packing
  unsigned long long packed =
      ((unsigned long long)sortable_key(bestV) << 32) |
      (unsigned)(NTGT - 1 - (tq * TSL + bestJ));   // tie -> smaller global index
  pk[tq * NPRED + pid] = packed;       // plain coalesced store, no init needed
}

// Single block: merge TS slices per pred, exact-div DIoU, full reduce, finalize.
__global__ __launch_bounds__(1024)
void diou_gather_finalize(const float4* __restrict__ pred,
                          const float4* __restrict__ tgt,
                          const unsigned long long* __restrict__ pk,
                          float* __restrict__ out) {
  __shared__ float sW[16];
  const int tid  = threadIdx.x;
  const int lane = tid & 63;

  float acc = 0.f;
  for (int pid = tid; pid < NPRED; pid += 1024) {
    unsigned long long best = pk[pid];
#pragma unroll
    for (int q = 1; q < TS; ++q) {
      unsigned long long v = pk[q * NPRED + pid];
      if (v > best) best = v;          // u64 max; low word favors smaller index
    }
    int    ix = NTGT - 1 - (int)(unsigned)(best & 0xFFFFFFFFu);
    float4 p  = pred[pid];
    float4 t  = tgt[ix];

    // reference reinterprets columns as (cx, cy, w, h)
    float phw = 0.5f * p.z, phh = 0.5f * p.w;
    float thw = 0.5f * t.z, thh = 0.5f * t.w;
    float pltx = p.x - phw, plty = p.y - phh;
    float prbx = p.x + phw, prby = p.y + phh;
    float tltx = t.x - thw, tlty = t.y - thh;
    float trbx = t.x + thw, trby = t.y + thh;

    float iw = fmaxf(fminf(prbx, trbx) - fmaxf(pltx, tltx), 0.f);
    float ih = fmaxf(fminf(prby, trby) - fmaxf(plty, tlty), 0.f);
    float inter = iw * ih;
    float parea = p.z * p.w;
    float tarea = t.z * t.w;
    float iou   = inter / (parea + tarea - inter + EPS);

    float dx = p.x - t.x, dy = p.y - t.y;
    float cd = dx * dx + dy * dy;

    float ew = fmaxf(prbx, trbx) - fminf(pltx, tltx);
    float eh = fmaxf(prby, trby) - fminf(plty, tlty);
    float diag = ew * ew + eh * eh;

    acc += iou - cd / (diag + EPS);
  }

  for (int off = 32; off > 0; off >>= 1) acc += __shfl_down(acc, off, 64);
  if (lane == 0) sW[tid >> 6] = acc;
  __syncthreads();
  if (tid == 0) {
    float s = 0.f;
#pragma unroll
    for (int i = 0; i < 16; ++i) s += sW[i];
    out[0] = 1.f - s * (1.f / (float)NPRED);
  }
}

extern "C" void kernel_launch(void* const* d_in, const int* in_sizes, int n_in,
                              void* d_out, int out_size, void* d_ws, size_t ws_size,
                              hipStream_t stream) {
  const float4* pred = (const float4*)d_in[0];
  const float4* tgt  = (const float4*)d_in[1];
  unsigned long long* pk = (unsigned long long*)d_ws;   // TS*NPRED*8 = 1 MB, fully written

  diou_argmax<<<GRID, BLOCK, 0, stream>>>(pred, tgt, pk);
  diou_gather_finalize<<<1, 1024, 0, stream>>>(pred, tgt, pk, (float*)d_out);
}